// Round 10
// baseline (710.715 us; speedup 1.0000x reference)
//
#include <hip/hip_runtime.h>

#define BATCH 256
#define NROW  512
#define CDIM  256
#define SPLIT 8
#define CHUNK (NROW / SPLIT)   // 64 rows per (b,s) block
#define WPB   4                // waves per block (256 threads)
#define RPW   (CHUNK / WPB)    // 16 rows per wave
#define CHK   8                // rows per register chunk (2 chunks, both prefetched)

#define DOT4(a, b) ((a).x * (b).x + (a).y * (b).y + (a).z * (b).z + (a).w * (b).w)

// ---------------------------------------------------------------------------
// KA: qk[b,:] = Wk^T (Wq @ P[b,id[b]] + bq).  256 blocks x 256 thr (1/batch).
// All loops batched-MLP style: 8 independent float4 loads in flight, no
// serial scalar-load dependence chains. Also zeroes cnt[b] for KB's
// last-block-finisher (visible to KB via kernel-boundary coherence).
// Score term Q.bk is constant over n -> softmax-invariant -> dropped.
// ---------------------------------------------------------------------------
__global__ __launch_bounds__(256) void qk_kernel(
    const float* __restrict__ P, const int* __restrict__ idx,
    const float* __restrict__ Wq, const float* __restrict__ bq,
    const float* __restrict__ Wk, float* __restrict__ qk,
    unsigned int* __restrict__ cnt) {
  const int b = blockIdx.x;
  const int t = threadIdx.x;
  const int lane = t & 63;
  const int w = t >> 6;

  __shared__ float s_psel[CDIM];
  __shared__ float s_q[CDIM];
  __shared__ float s_qkp[WPB][CDIM];

  if (t == 0) cnt[b] = 0u;
  s_psel[t] = P[((size_t)b * NROW + (size_t)idx[b]) * CDIM + t];
  __syncthreads();

  const float4 pr4 = ((const float4*)s_psel)[lane];
  const int d0 = w * 64;

  // Q[d] for wave's 64-row slice: 8 coalesced float4 row-loads in flight
#pragma unroll
  for (int g = 0; g < 8; ++g) {
    float4 wq[8];
#pragma unroll
    for (int i = 0; i < 8; ++i)
      wq[i] = ((const float4*)(Wq + (size_t)(d0 + g * 8 + i) * CDIM))[lane];
#pragma unroll
    for (int i = 0; i < 8; ++i) {
      float part = DOT4(wq[i], pr4);
#pragma unroll
      for (int mm = 32; mm >= 1; mm >>= 1) part += __shfl_xor(part, mm, 64);
      if (lane == 0) s_q[d0 + g * 8 + i] = part + bq[d0 + g * 8 + i];
    }
  }
  __syncthreads();

  // qk[e] = sum_d Q[d]*Wk[d,e]: wave w covers d in [d0,d0+64), float4 over e,
  // 8-deep unroll keeps 8 coalesced loads in flight; merge partials in LDS.
  {
    float4 acc = make_float4(0.f, 0.f, 0.f, 0.f);
#pragma unroll 8
    for (int dd = 0; dd < 64; ++dd) {
      const int d = d0 + dd;
      const float qd = s_q[d];
      const float4 wk4 = ((const float4*)(Wk + (size_t)d * CDIM))[lane];
      acc.x += qd * wk4.x; acc.y += qd * wk4.y;
      acc.z += qd * wk4.z; acc.w += qd * wk4.w;
    }
    ((float4*)s_qkp[w])[lane] = acc;
  }
  __syncthreads();

  qk[(size_t)b * CDIM + t] =
      s_qkp[0][t] + s_qkp[1][t] + s_qkp[2][t] + s_qkp[3][t];
}

// ---------------------------------------------------------------------------
// KB: per (b,s): online softmax + ctx partial over 64 rows (proven 21.8us),
// then last-block-finisher: 8th block of each batch merges partials and
// applies Wv + bv -> out. 2048 blocks x 256 thr.
// ---------------------------------------------------------------------------
__global__ __launch_bounds__(256, 4) void attn_kernel(
    const float* __restrict__ P, const float* __restrict__ qk,
    const float* __restrict__ Wv, const float* __restrict__ bv,
    float* __restrict__ ctxp, float* __restrict__ mp, float* __restrict__ lp,
    unsigned int* __restrict__ cnt, float* __restrict__ out) {
  const int bs = blockIdx.x;
  const int b = bs >> 3;
  const int s = bs & (SPLIT - 1);
  const int t = threadIdx.x;
  const int lane = t & 63;
  const int w = t >> 6;

  __shared__ float s_ctx[WPB][CDIM];
  __shared__ float s_m[WPB], s_l[WPB];
  __shared__ float s_ctxn[CDIM];
  __shared__ int s_last;

  const float* Pw =
      P + ((size_t)b * NROW + (size_t)s * CHUNK + (size_t)w * RPW) * CDIM;

  const float4 qk4 = ((const float4*)(qk + (size_t)b * CDIM))[lane];

  // issue ALL 16 rows' loads before any consume (max MLP)
  float4 pv0[CHK], pv1[CHK];
#pragma unroll
  for (int i = 0; i < CHK; ++i)
    pv0[i] = ((const float4*)(Pw + (size_t)i * CDIM))[lane];
#pragma unroll
  for (int i = 0; i < CHK; ++i)
    pv1[i] = ((const float4*)(Pw + (size_t)(CHK + i) * CDIM))[lane];

  float m = -1e30f, l = 0.f;
  float4 ctx = make_float4(0.f, 0.f, 0.f, 0.f);

#define CONSUME(cur)                                                         \
  {                                                                          \
    float sc[CHK];                                                           \
    _Pragma("unroll") for (int i = 0; i < CHK; ++i) {                        \
      float part = DOT4(cur[i], qk4);                                        \
      _Pragma("unroll") for (int mm = 32; mm >= 1; mm >>= 1)                 \
          part += __shfl_xor(part, mm, 64);                                  \
      sc[i] = part;                                                          \
    }                                                                        \
    float cmax = sc[0];                                                      \
    _Pragma("unroll") for (int i = 1; i < CHK; ++i)                          \
        cmax = fmaxf(cmax, sc[i]);                                           \
    const float mnew = fmaxf(m, cmax);                                       \
    const float scale = __expf(m - mnew); /* first iter: ~exp(-inf)=0 */     \
    l *= scale;                                                              \
    ctx.x *= scale; ctx.y *= scale; ctx.z *= scale; ctx.w *= scale;          \
    _Pragma("unroll") for (int i = 0; i < CHK; ++i) {                        \
      const float p = __expf(sc[i] - mnew);                                  \
      l += p;                                                                \
      ctx.x += p * cur[i].x; ctx.y += p * cur[i].y;                          \
      ctx.z += p * cur[i].z; ctx.w += p * cur[i].w;                          \
    }                                                                        \
    m = mnew;                                                                \
  }

  CONSUME(pv0);
  CONSUME(pv1);
#undef CONSUME

  ((float4*)s_ctx[w])[lane] = ctx;
  if (lane == 0) { s_m[w] = m; s_l[w] = l; }
  __syncthreads();

  const float mb = fmaxf(fmaxf(s_m[0], s_m[1]), fmaxf(s_m[2], s_m[3]));
  const float co0 = __expf(s_m[0] - mb), co1 = __expf(s_m[1] - mb);
  const float co2 = __expf(s_m[2] - mb), co3 = __expf(s_m[3] - mb);
  ctxp[(size_t)bs * CDIM + t] = co0 * s_ctx[0][t] + co1 * s_ctx[1][t] +
                                co2 * s_ctx[2][t] + co3 * s_ctx[3][t];
  if (t == 0) {
    mp[bs] = mb;
    lp[bs] = co0 * s_l[0] + co1 * s_l[1] + co2 * s_l[2] + co3 * s_l[3];
  }

  // ---- last-block finisher (standard threadfence-reduction pattern) ----
  __threadfence();   // release: make this block's partials device-visible
  __syncthreads();
  if (t == 0) {
    const unsigned int old = atomicAdd(&cnt[b], 1u);
    s_last = (old == SPLIT - 1) ? 1 : 0;
  }
  __syncthreads();
  if (!s_last) return;

  __threadfence();   // acquire: see all 8 blocks' partials

  {
    float ms[SPLIT];
    float mg = -3.4e38f;
#pragma unroll
    for (int i = 0; i < SPLIT; ++i) {
      ms[i] = mp[b * SPLIT + i];
      mg = fmaxf(mg, ms[i]);
    }
    float lg = 0.f, c = 0.f;
#pragma unroll
    for (int i = 0; i < SPLIT; ++i) {
      const float ww = __expf(ms[i] - mg);
      lg += lp[b * SPLIT + i] * ww;
      c += ctxp[(size_t)(b * SPLIT + i) * CDIM + t] * ww;  // coalesced
    }
    s_ctxn[t] = c / lg;
  }
  __syncthreads();

  // out[d] = dot(Wv[d,:], ctxn) + bv[d]; wave w owns d in [w*64, w*64+64),
  // 8 coalesced float4 row-loads in flight + butterfly (Wv is L2-resident).
  {
    const float4 cx4 = ((const float4*)s_ctxn)[lane];
    const int d0 = w * 64;
#pragma unroll
    for (int g = 0; g < 8; ++g) {
      float4 wv[8];
#pragma unroll
      for (int i = 0; i < 8; ++i)
        wv[i] = ((const float4*)(Wv + (size_t)(d0 + g * 8 + i) * CDIM))[lane];
#pragma unroll
      for (int i = 0; i < 8; ++i) {
        float part = DOT4(wv[i], cx4);
#pragma unroll
        for (int mm = 32; mm >= 1; mm >>= 1) part += __shfl_xor(part, mm, 64);
        if (lane == 0) {
          const int d = d0 + g * 8 + i;
          out[(size_t)b * CDIM + d] = part + bv[d];
        }
      }
    }
  }
}

// ---------------------------------------------------------------------------
extern "C" void kernel_launch(void* const* d_in, const int* in_sizes, int n_in,
                              void* d_out, int out_size, void* d_ws,
                              size_t ws_size, hipStream_t stream) {
  const float* P  = (const float*)d_in[0];
  const int*  idx = (const int*)d_in[1];   // jax default x64-off: int32
  const float* Wq = (const float*)d_in[2];
  const float* bq = (const float*)d_in[3];
  const float* Wk = (const float*)d_in[4];
  // d_in[5] = bk: constant score shift per batch -> softmax-invariant -> unused
  const float* Wv = (const float*)d_in[6];
  const float* bv = (const float*)d_in[7];
  float* out = (float*)d_out;

  float* ws   = (float*)d_ws;
  float* qk   = ws;                            // B*C       = 65536 floats
  float* ctxp = qk + BATCH * CDIM;             // B*SPLIT*C = 524288 floats
  float* mp   = ctxp + BATCH * SPLIT * CDIM;   // B*SPLIT   = 2048
  float* lp   = mp + BATCH * SPLIT;            // B*SPLIT   = 2048
  unsigned int* cnt = (unsigned int*)(lp + BATCH * SPLIT);  // B counters

  qk_kernel<<<BATCH, 256, 0, stream>>>(P, idx, Wq, bq, Wk, qk, cnt);
  attn_kernel<<<BATCH * SPLIT, 256, 0, stream>>>(P, qk, Wv, bv, ctxp, mp, lp,
                                                 cnt, out);
}

// Round 11
// 223.381 us; speedup vs baseline: 3.1816x; 3.1816x over previous
//
#include <hip/hip_runtime.h>

#define BATCH 256
#define NROW  512
#define CDIM  256
#define WAVES 16               // 1024 threads = 16 waves = 4 waves/SIMD
#define RPW   (NROW / WAVES)   // 32 rows per wave
#define CHK   8                // rows per register chunk (ping-pong)
#define NCHK  (RPW / CHK)      // 4 chunks per wave

#define DOT4(a, b) ((a).x * (b).x + (a).y * (b).y + (a).z * (b).z + (a).w * (b).w)

// ---------------------------------------------------------------------------
// ONE kernel, one block per batch, 1024 threads (16 waves, 4/SIMD).
//  prologue : qk = Wk^T (Wq @ P[b,id[b]] + bq)   (all 16 waves participate)
//  stream   : wave w owns rows [w*32, w*32+32), online softmax, 4 ping-pong
//             register chunks of 8 rows. P read EXACTLY once. No fences,
//             no atomics, no cross-block communication.
//  epilogue : 16-way LDS merge, out = Wv @ (ctx/l) + bv.
// Q.bk score term is constant over n -> softmax-invariant -> dropped.
// ---------------------------------------------------------------------------
__global__ __launch_bounds__(1024, 4) void attn_mono_kernel(
    const float* __restrict__ P, const int* __restrict__ idx,
    const float* __restrict__ Wq, const float* __restrict__ bq,
    const float* __restrict__ Wk, const float* __restrict__ Wv,
    const float* __restrict__ bv, float* __restrict__ out) {
  const int b = blockIdx.x;
  const int t = threadIdx.x;
  const int lane = t & 63;
  const int w = t >> 6;  // 0..15

  __shared__ float s_psel[CDIM];
  __shared__ float s_q[CDIM];
  __shared__ float s_qk[CDIM];
  __shared__ float s_wavebuf[WAVES][CDIM];  // qk partials, then ctx partials
  __shared__ float s_m[WAVES], s_l[WAVES];
  __shared__ float s_ctxn[CDIM];

  const float* Pw = P + ((size_t)b * NROW + (size_t)w * RPW) * CDIM;

  // ---- issue chunk-0 stream loads FIRST (hide HBM latency under prologue)
  float4 pv0[CHK], pv1[CHK];
#pragma unroll
  for (int i = 0; i < CHK; ++i)
    pv0[i] = ((const float4*)(Pw + (size_t)i * CDIM))[lane];

  // ---- prologue: stage p_sel ----
  if (t < CDIM)
    s_psel[t] = P[((size_t)b * NROW + (size_t)idx[b]) * CDIM + t];
  __syncthreads();

  const float4 pr4 = ((const float4*)s_psel)[lane];
  const int d0 = w * 16;  // this wave's 16-row slice of the 256 outputs

  // ---- Q[d] = dot(Wq[d,:], psel) + bq[d]: 2 groups x 8 rows, butterfly ----
#pragma unroll
  for (int g = 0; g < 2; ++g) {
    float4 wq[8];
#pragma unroll
    for (int i = 0; i < 8; ++i)
      wq[i] = ((const float4*)(Wq + (size_t)(d0 + g * 8 + i) * CDIM))[lane];
#pragma unroll
    for (int i = 0; i < 8; ++i) {
      float part = DOT4(wq[i], pr4);
#pragma unroll
      for (int mm = 32; mm >= 1; mm >>= 1) part += __shfl_xor(part, mm, 64);
      if (lane == 0) s_q[d0 + g * 8 + i] = part + bq[d0 + g * 8 + i];
    }
  }
  __syncthreads();

  // ---- qk[e] = sum_d Q[d]*Wk[d,e]: wave w covers its 16 d-rows ----
  {
    float4 acc = make_float4(0.f, 0.f, 0.f, 0.f);
#pragma unroll
    for (int dd = 0; dd < 16; ++dd) {
      const int d = d0 + dd;
      const float qd = s_q[d];  // LDS broadcast
      const float4 wk4 = ((const float4*)(Wk + (size_t)d * CDIM))[lane];
      acc.x += qd * wk4.x; acc.y += qd * wk4.y;
      acc.z += qd * wk4.z; acc.w += qd * wk4.w;
    }
    ((float4*)s_wavebuf[w])[lane] = acc;
  }
  __syncthreads();

  if (t < CDIM) {
    float a = 0.f;
#pragma unroll
    for (int i = 0; i < WAVES; ++i) a += s_wavebuf[i][t];
    s_qk[t] = a;
  }
  __syncthreads();

  const float4 qk4 = ((const float4*)s_qk)[lane];

  // ---- stream: online softmax over 32 rows, 4 ping-pong chunks of 8 ----
  float m = -1e30f, l = 0.f;
  float4 ctx = make_float4(0.f, 0.f, 0.f, 0.f);

#define PREFETCH(dst, chn)                                                   \
  {                                                                          \
    _Pragma("unroll") for (int i = 0; i < CHK; ++i) dst[i] =                 \
        ((const float4*)(Pw + (size_t)((chn) * CHK + i) * CDIM))[lane];      \
  }

#define CONSUME(cur)                                                         \
  {                                                                          \
    float sc[CHK];                                                           \
    _Pragma("unroll") for (int i = 0; i < CHK; ++i) {                        \
      float part = DOT4(cur[i], qk4);                                        \
      _Pragma("unroll") for (int mm = 32; mm >= 1; mm >>= 1)                 \
          part += __shfl_xor(part, mm, 64);                                  \
      sc[i] = part;                                                          \
    }                                                                        \
    float cmax = sc[0];                                                      \
    _Pragma("unroll") for (int i = 1; i < CHK; ++i)                          \
        cmax = fmaxf(cmax, sc[i]);                                           \
    const float mnew = fmaxf(m, cmax);                                       \
    const float scale = __expf(m - mnew); /* first iter: exp(-huge)=0 */     \
    l *= scale;                                                              \
    ctx.x *= scale; ctx.y *= scale; ctx.z *= scale; ctx.w *= scale;          \
    _Pragma("unroll") for (int i = 0; i < CHK; ++i) {                        \
      const float p = __expf(sc[i] - mnew);                                  \
      l += p;                                                                \
      ctx.x += p * cur[i].x; ctx.y += p * cur[i].y;                          \
      ctx.z += p * cur[i].z; ctx.w += p * cur[i].w;                          \
    }                                                                        \
    m = mnew;                                                                \
  }

#pragma unroll
  for (int cc = 0; cc < NCHK; cc += 2) {
    if (cc + 1 < NCHK) PREFETCH(pv1, cc + 1);
    CONSUME(pv0);
    if (cc + 2 < NCHK) PREFETCH(pv0, cc + 2);
    if (cc + 1 < NCHK) CONSUME(pv1);
  }
#undef PREFETCH
#undef CONSUME

  // ---- 16-way cross-wave merge (s_wavebuf reused for ctx partials) ----
  ((float4*)s_wavebuf[w])[lane] = ctx;
  if (lane == 0) { s_m[w] = m; s_l[w] = l; }
  __syncthreads();

  if (t < CDIM) {
    float mg = s_m[0];
#pragma unroll
    for (int i = 1; i < WAVES; ++i) mg = fmaxf(mg, s_m[i]);
    float lg = 0.f, c = 0.f;
#pragma unroll
    for (int i = 0; i < WAVES; ++i) {
      const float co = __expf(s_m[i] - mg);
      lg += co * s_l[i];
      c  += co * s_wavebuf[i][t];
    }
    s_ctxn[t] = c / lg;
  }
  __syncthreads();

  // ---- out[d] = dot(Wv[d,:], ctxn) + bv[d]: wave w -> its 16 d-rows ----
  {
    const float4 cx4 = ((const float4*)s_ctxn)[lane];
#pragma unroll
    for (int g = 0; g < 2; ++g) {
      float4 wv[8];
#pragma unroll
      for (int i = 0; i < 8; ++i)
        wv[i] = ((const float4*)(Wv + (size_t)(d0 + g * 8 + i) * CDIM))[lane];
#pragma unroll
      for (int i = 0; i < 8; ++i) {
        float part = DOT4(wv[i], cx4);
#pragma unroll
        for (int mm = 32; mm >= 1; mm >>= 1) part += __shfl_xor(part, mm, 64);
        if (lane == 0) {
          const int d = d0 + g * 8 + i;
          out[(size_t)b * CDIM + d] = part + bv[d];
        }
      }
    }
  }
}

// ---------------------------------------------------------------------------
extern "C" void kernel_launch(void* const* d_in, const int* in_sizes, int n_in,
                              void* d_out, int out_size, void* d_ws,
                              size_t ws_size, hipStream_t stream) {
  const float* P  = (const float*)d_in[0];
  const int*  idx = (const int*)d_in[1];   // jax default x64-off: int32
  const float* Wq = (const float*)d_in[2];
  const float* bq = (const float*)d_in[3];
  const float* Wk = (const float*)d_in[4];
  // d_in[5] = bk: constant score shift per batch -> softmax-invariant -> unused
  const float* Wv = (const float*)d_in[6];
  const float* bv = (const float*)d_in[7];
  float* out = (float*)d_out;

  attn_mono_kernel<<<BATCH, 1024, 0, stream>>>(P, idx, Wq, bq, Wk, Wv, bv,
                                               out);
}